// Round 8
// baseline (404.139 us; speedup 1.0000x reference)
//
#include <hip/hip_runtime.h>
#include <math.h>

#define NB 16
#define NA 1024
#define NT 512
#define ND 256
#define PAD 32

typedef short bf8_t __attribute__((ext_vector_type(8)));
typedef float f4_t __attribute__((ext_vector_type(4)));

__device__ __forceinline__ float bf2f(ushort u) {
    union { unsigned int i; float f; } v; v.i = ((unsigned int)u) << 16; return v.f;
}
__device__ __forceinline__ ushort f2bf(float f) {
    union { float f; unsigned int i; } v; v.f = f;
    unsigned int x = v.i;
    unsigned int r = (x + 0x7fffu + ((x >> 16) & 1u)) >> 16;
    return (ushort)r;
}
__device__ __forceinline__ void gl_lds16(const void* g, void* l) {
    __builtin_amdgcn_global_load_lds(
        (const __attribute__((address_space(1))) unsigned int*)g,
        (__attribute__((address_space(3))) unsigned int*)l, 16, 0, 0);
}

// Activation layout (k-major, padded): chunk(b, qq, l_phys) at
//   ((b*32 + qq)*Lp + l_phys)*8 ushorts, qq = ch>>3, Lp = L + 64.

// ---------------- setup: gathers + pad zero + a2/t2 zero + weight repack ----
__global__ void __launch_bounds__(256)
setup_kernel(const int* __restrict__ art_w, const int* __restrict__ tpl_w,
             const float* __restrict__ emb,
             ushort* __restrict__ art_a, ushort* __restrict__ art_b,
             ushort* __restrict__ tpl_a, ushort* __restrict__ tpl_b,
             const float* __restrict__ exp_w, const float* __restrict__ ref_w,
             ushort* __restrict__ wpack,
             float* __restrict__ a2, float* __restrict__ t2) {
    __shared__ float tile[64][65];
    int bid = blockIdx.x;
    int tid = threadIdx.x;

    if (bid < 2048) {                       // article gather
        int idx = bid * 256 + tid;
        int l = idx & (NA - 1);
        int bq = idx >> 10;
        int qq = bq & 31, b = bq >> 5;
        int wd = art_w[b * NA + l];
        const float4* src = (const float4*)(emb + (size_t)wd * ND + qq * 8);
        float4 v0 = src[0], v1 = src[1];
        ushort o[8];
        o[0]=f2bf(v0.x); o[1]=f2bf(v0.y); o[2]=f2bf(v0.z); o[3]=f2bf(v0.w);
        o[4]=f2bf(v1.x); o[5]=f2bf(v1.y); o[6]=f2bf(v1.z); o[7]=f2bf(v1.w);
        *(uint4*)(art_a + ((size_t)bq * (NA + 64) + PAD + l) * 8) = *(uint4*)o;
        return;
    }
    bid -= 2048;
    if (bid < 1024) {                       // template gather
        int j = bid * 256 + tid;
        int l = j & (NT - 1);
        int bq = j >> 9;
        int qq = bq & 31, b = bq >> 5;
        int wd = tpl_w[b * NT + l];
        const float4* src = (const float4*)(emb + (size_t)wd * ND + qq * 8);
        float4 v0 = src[0], v1 = src[1];
        ushort o[8];
        o[0]=f2bf(v0.x); o[1]=f2bf(v0.y); o[2]=f2bf(v0.z); o[3]=f2bf(v0.w);
        o[4]=f2bf(v1.x); o[5]=f2bf(v1.y); o[6]=f2bf(v1.z); o[7]=f2bf(v1.w);
        *(uint4*)(tpl_a + ((size_t)bq * (NT + 64) + PAD + l) * 8) = *(uint4*)o;
        return;
    }
    bid -= 1024;
    if (bid < 512) {                        // pad zeroing
        int j = bid * 256 + tid;
        int y = j >> 15;
        int rem = j & 32767;
        ushort* p = (y == 0) ? art_a : (y == 1) ? art_b : (y == 2) ? tpl_a : tpl_b;
        int L = (y < 2) ? NA : NT;
        int Lp = L + 2 * PAD;
        int plane = rem >> 6;
        int row_in = rem & 63;
        int slab = (row_in < PAD) ? row_in : L + row_in;
        uint4 z = make_uint4(0, 0, 0, 0);
        *(uint4*)(p + ((size_t)plane * Lp + slab) * 8) = z;
        return;
    }
    bid -= 512;
    if (bid < 24) {                         // a2/t2 zeroing (24576 floats)
        int i = (bid * 256 + tid) * 4;
        float4 z = make_float4(0.f, 0.f, 0.f, 0.f);
        if (i < NB * NA) *(float4*)(a2 + i) = z;
        else             *(float4*)(t2 + i - NB * NA) = z;
        return;
    }
    bid -= 24;
    // weight repack: bid in [0,960)
    {
        int li = bid / 96;
        int r = bid % 96;
        int gk = r >> 3;                    // 0..11
        int gc = r & 7;                     // 0..7
        const float* src = (li < 7) ? exp_w + (size_t)li * 3 * ND * 512
                                    : ref_w + (size_t)(li - 7) * 3 * ND * 512;
        int k0g = gk * 64, c0 = gc * 64;
        #pragma unroll
        for (int p = 0; p < 4; ++p) {
            int kr = p * 16 + (tid >> 4);
            int cc = (tid & 15) * 4;
            *(float4*)&tile[kr][cc] =
                *(const float4*)(src + (size_t)(k0g + kr) * 512 + c0 + cc);
        }
        __syncthreads();
        int tap = k0g >> 8, kl0 = k0g & 255, kc0 = kl0 >> 5;
        int ag = c0 >> 8, cb = (c0 & 255) >> 6;
        int kg = tid >> 5, idx = tid & 31;
        int kc = kc0 + (kg >> 2), qq = kg & 3;
        #pragma unroll
        for (int h = 0; h < 2; ++h) {
            int w64 = idx + h * 32;
            int cprime = h * 64 + ag * 32 + idx;
            ushort o[8];
            #pragma unroll
            for (int j = 0; j < 8; ++j) o[j] = f2bf(tile[kg * 8 + j][w64]);
            ushort* d = wpack +
                (((((size_t)(li * 4 + cb) * 3 + tap) * 8 + kc) * 4 + qq) * 128 + cprime) * 8;
            *(uint4*)d = *(uint4*)o;
        }
    }
}

// ---------------- fused conv-GLU-residual, bf16 MFMA (art+tpl fused) --------
// True double-buffered A staging: sync -> issue stage(kc+1) -> compute(kc).
// Prefetch is in flight for a whole compute phase before the next barrier's
// vmcnt(0) drain -> drain ~0. One barrier per K=32 phase.
__global__ void __launch_bounds__(256, 4)
conv_glu_mfma(const ushort* __restrict__ art_x, ushort* __restrict__ art_y,
              const ushort* __restrict__ tpl_x, ushort* __restrict__ tpl_y,
              const ushort* __restrict__ wp, const float* __restrict__ bias,
              int dil, int last, float* __restrict__ a2, float* __restrict__ t2) {
    __shared__ char smem[34816];
    ushort* Abuf = (ushort*)smem;           // 2 x 12 KB staging buffers
    float* ylds = (float*)smem;             // [128][68] fp32 epilogue (aliases)

    const int tid = threadIdx.x;
    const int w = tid >> 6, lane = tid & 63;
    const int wm = w >> 1, wn = w & 1;
    const int q = lane >> 4, l15 = lane & 15;

    const int id = blockIdx.x;
    const int cb = (id >> 3) & 3;
    const int pb = ((id >> 5) << 3) | (id & 7);   // 0..191
    const int plane = pb % 12;
    const int b = pb / 12;
    const int b32 = b * 32;

    int Lp, l0;
    const ushort* xb;
    ushort* yb;
    float* sq;
    int sqbase;
    if (plane < 8) {
        Lp = NA + 2 * PAD; l0 = plane * 128;
        xb = art_x; yb = art_y; sq = a2; sqbase = b * NA + l0;
    } else {
        Lp = NT + 2 * PAD; l0 = (plane - 8) * 128;
        xb = tpl_x; yb = tpl_y; sq = t2; sqbase = b * NT + l0;
    }
    const ushort* wl = wp + (size_t)cb * 98304;   // 3*8*4*128*8
    const int boff = (q * 128 + wn * 64 + l15) * 8;

    f4_t acc[4][4];
    #pragma unroll
    for (int i = 0; i < 4; ++i)
        #pragma unroll
        for (int j = 0; j < 4; ++j)
            acc[i][j] = (f4_t){0.f, 0.f, 0.f, 0.f};

    // prologue: stage kc=0 into buf 0
    #pragma unroll
    for (int s3 = 0; s3 < 3; ++s3) {
        int s = w + s3 * 4;                // 0..11
        int qq = s / 3;
        int rphys = l0 + (s % 3) * 64 + lane;
        gl_lds16(xb + ((size_t)(b32 + qq) * Lp + rphys) * 8, Abuf + s * 512);
    }

    for (int kc = 0; kc < 8; ++kc) {
        __syncthreads();                   // stage(kc) ready; prev compute done
        if (kc < 7) {                      // prefetch stage(kc+1) into other buf
            ushort* dst = Abuf + ((kc + 1) & 1) * 6144;
            #pragma unroll
            for (int s3 = 0; s3 < 3; ++s3) {
                int s = w + s3 * 4;
                int qq = (kc + 1) * 4 + s / 3;
                int rphys = l0 + (s % 3) * 64 + lane;
                gl_lds16(xb + ((size_t)(b32 + qq) * Lp + rphys) * 8, dst + s * 512);
            }
        }
        const ushort* Ah = Abuf + (kc & 1) * 6144;
        const ushort* wkc = wl + kc * 4096 + boff;
        #pragma unroll
        for (int t = 0; t < 3; ++t) {
            bf8_t bfr[4];
            #pragma unroll
            for (int nt = 0; nt < 4; ++nt)
                bfr[nt] = *(const bf8_t*)(wkc + t * 32768 + nt * 128);
            const int sh = (t - 1) * dil;
            bf8_t af[4];
            #pragma unroll
            for (int mt = 0; mt < 4; ++mt)
                af[mt] = *(const bf8_t*)(Ah + (q * 192 + 32 + sh + wm * 64 + mt * 16 + l15) * 8);
            #pragma unroll
            for (int mt = 0; mt < 4; ++mt)
                #pragma unroll
                for (int nt = 0; nt < 4; ++nt)
                    acc[mt][nt] = __builtin_amdgcn_mfma_f32_16x16x32_bf16(
                        af[mt], bfr[nt], acc[mt][nt], 0, 0, 0);
        }
    }
    __syncthreads();

    // GLU epilogue into LDS (fp32), row stride 68 (conflict-free b128 reads)
    #pragma unroll
    for (int nt = 0; nt < 2; ++nt) {
        const int cl = wn * 32 + nt * 16 + l15;
        const int chan = cb * 64 + cl;
        const float ba = bias[chan];
        const float bg2 = bias[chan + 256];
        #pragma unroll
        for (int mt = 0; mt < 4; ++mt) {
            #pragma unroll
            for (int r = 0; r < 4; ++r) {
                const int row = wm * 64 + mt * 16 + q * 4 + r;
                float av = acc[mt][nt][r] + ba;
                float gv = acc[mt][nt + 2][r] + bg2;
                ylds[row * 68 + cl] = av / (1.f + __expf(-gv));
            }
        }
    }
    __syncthreads();

    // residual add + bf16 store, k-major coalesced (+ fused sumsq on last)
    float ss = 0.f;
    #pragma unroll
    for (int p = 0; p < 4; ++p) {
        int u = p * 256 + tid;
        int cl8 = u >> 7;                  // 0..7 plane-chunk within cb
        int row = u & 127;
        size_t go = ((size_t)(b32 + cb * 8 + cl8) * Lp + l0 + PAD + row) * 8;
        ushort xv[8]; *(uint4*)xv = *(const uint4*)(xb + go);
        float4 y0 = *(float4*)&ylds[row * 68 + cl8 * 8];
        float4 y1 = *(float4*)&ylds[row * 68 + cl8 * 8 + 4];
        ushort ov[8];
        ov[0]=f2bf(bf2f(xv[0])+y0.x); ov[1]=f2bf(bf2f(xv[1])+y0.y);
        ov[2]=f2bf(bf2f(xv[2])+y0.z); ov[3]=f2bf(bf2f(xv[3])+y0.w);
        ov[4]=f2bf(bf2f(xv[4])+y1.x); ov[5]=f2bf(bf2f(xv[5])+y1.y);
        ov[6]=f2bf(bf2f(xv[6])+y1.z); ov[7]=f2bf(bf2f(xv[7])+y1.w);
        *(uint4*)(yb + go) = *(uint4*)ov;
        if (last) {
            #pragma unroll
            for (int j = 0; j < 8; ++j) { float f = bf2f(ov[j]); ss += f * f; }
        }
    }
    if (last) {
        float* ssred = (float*)smem;
        __syncthreads();                   // all ylds reads done
        ssred[tid] = ss;
        __syncthreads();
        if (tid < 128)
            atomicAdd(&sq[sqbase + tid], ssred[tid] + ssred[tid + 128]);
    }
}

// ---------------- distance + exp + row max, bf16 MFMA (M=64, dbuf) ----------
__global__ void __launch_bounds__(256, 4)
dist_rowmax_mfma(const ushort* __restrict__ art, const ushort* __restrict__ tpl,
                 const float* __restrict__ a2, const float* __restrict__ t2,
                 const float* __restrict__ amask, const float* __restrict__ tmask,
                 float* __restrict__ rmaxp) {
    __shared__ ushort Als[2][4 * 512];     // n = qq*64 + r
    __shared__ ushort Bls[2][8 * 512];     // n = qq*128 + r
    __shared__ float red[2][64];

    const int tid = threadIdx.x;
    const int w = tid >> 6, lane = tid & 63;
    const int wm = w >> 1, wn = w & 1;
    const int q = lane >> 4, l15 = lane & 15;

    const int id = blockIdx.x;
    const int b = (id & 7) | (((id >> 3) & 1) << 3);
    const int rest = id >> 4;              // 0..63
    const int a0 = (rest & 15) * 64;
    const int tplane = rest >> 4;          // 0..3
    const int t0 = tplane * 128;
    const int b32 = b * 32;
    const int LpA = NA + 2 * PAD, LpT = NT + 2 * PAD;

    float a2v[2][4], amv[2][4];
    #pragma unroll
    for (int mt = 0; mt < 2; ++mt)
        #pragma unroll
        for (int r = 0; r < 4; ++r) {
            int row = a0 + wm * 32 + mt * 16 + q * 4 + r;
            a2v[mt][r] = a2[b * NA + row];
            amv[mt][r] = amask[b * NA + row];
        }

    f4_t acc[2][4];
    #pragma unroll
    for (int i = 0; i < 2; ++i)
        #pragma unroll
        for (int j = 0; j < 4; ++j)
            acc[i][j] = (f4_t){0.f, 0.f, 0.f, 0.f};

    // prologue stage kb=0
    #pragma unroll
    for (int s3 = 0; s3 < 3; ++s3) {
        int s = w + s3 * 4;
        if (s < 4) {
            gl_lds16(art + ((size_t)(b32 + s) * LpA + PAD + a0 + lane) * 8,
                     Als[0] + s * 512);
        } else {
            int s2 = s - 4;
            int qq = s2 >> 1;
            int r0 = (s2 & 1) * 64;
            gl_lds16(tpl + ((size_t)(b32 + qq) * LpT + PAD + t0 + r0 + lane) * 8,
                     Bls[0] + s2 * 512);
        }
    }

    for (int kb = 0; kb < 8; ++kb) {
        __syncthreads();
        if (kb < 7) {
            int nb = (kb + 1) & 1;
            #pragma unroll
            for (int s3 = 0; s3 < 3; ++s3) {
                int s = w + s3 * 4;
                if (s < 4) {
                    int qq = (kb + 1) * 4 + s;
                    gl_lds16(art + ((size_t)(b32 + qq) * LpA + PAD + a0 + lane) * 8,
                             Als[nb] + s * 512);
                } else {
                    int s2 = s - 4;
                    int qq = (kb + 1) * 4 + (s2 >> 1);
                    int r0 = (s2 & 1) * 64;
                    gl_lds16(tpl + ((size_t)(b32 + qq) * LpT + PAD + t0 + r0 + lane) * 8,
                             Bls[nb] + s2 * 512);
                }
            }
        }
        const ushort* Ab = Als[kb & 1];
        const ushort* Bb = Bls[kb & 1];
        bf8_t af[2], bfr[4];
        #pragma unroll
        for (int mt = 0; mt < 2; ++mt)
            af[mt] = *(const bf8_t*)(Ab + (q * 64 + wm * 32 + mt * 16 + l15) * 8);
        #pragma unroll
        for (int nt = 0; nt < 4; ++nt)
            bfr[nt] = *(const bf8_t*)(Bb + (q * 128 + wn * 64 + nt * 16 + l15) * 8);
        #pragma unroll
        for (int mt = 0; mt < 2; ++mt)
            #pragma unroll
            for (int nt = 0; nt < 4; ++nt)
                acc[mt][nt] = __builtin_amdgcn_mfma_f32_16x16x32_bf16(
                    af[mt], bfr[nt], acc[mt][nt], 0, 0, 0);
    }

    float rm[2][4];
    #pragma unroll
    for (int mt = 0; mt < 2; ++mt)
        #pragma unroll
        for (int r = 0; r < 4; ++r) rm[mt][r] = 0.f;

    #pragma unroll
    for (int nt = 0; nt < 4; ++nt) {
        int t = t0 + wn * 64 + nt * 16 + l15;
        float t2v = t2[b * NT + t];
        float tmv = tmask[b * NT + t];
        #pragma unroll
        for (int mt = 0; mt < 2; ++mt)
            #pragma unroll
            for (int r = 0; r < 4; ++r) {
                float d = a2v[mt][r] + t2v - 2.f * acc[mt][nt][r];
                d = fmaxf(d, 0.f);
                float s = __expf(-d) * amv[mt][r] * tmv;
                rm[mt][r] = fmaxf(rm[mt][r], s);
            }
    }
    #pragma unroll
    for (int mt = 0; mt < 2; ++mt)
        #pragma unroll
        for (int r = 0; r < 4; ++r) {
            float v = rm[mt][r];
            #pragma unroll
            for (int off = 1; off < 16; off <<= 1)
                v = fmaxf(v, __shfl_xor(v, off));
            rm[mt][r] = v;
        }
    if (l15 == 0) {
        #pragma unroll
        for (int mt = 0; mt < 2; ++mt)
            #pragma unroll
            for (int r = 0; r < 4; ++r)
                red[wn][wm * 32 + mt * 16 + q * 4 + r] = rm[mt][r];
    }
    __syncthreads();
    if (tid < 64)
        rmaxp[((size_t)tplane * NB + b) * NA + a0 + tid] =
            fmaxf(red[0][tid], red[1][tid]);
}

// ---------------- top-10 + MLP ---------------------------------------------
__global__ void __launch_bounds__(256)
topk_mlp_kernel(const float* __restrict__ rmaxp,
                const float* __restrict__ ff1_w, const float* __restrict__ ff1_b,
                const float* __restrict__ ff2_w, const float* __restrict__ ff2_b,
                float* __restrict__ out) {
    __shared__ float vals[NA];
    __shared__ float top[10];
    __shared__ float h[10];
    __shared__ float rv[4];
    __shared__ int ri[4];

    int b = blockIdx.x;
    int tid = threadIdx.x;
    int lane = tid & 63, wv = tid >> 6;
    for (int i = tid; i < NA; i += 256) {
        float m = rmaxp[(size_t)b * NA + i];
        m = fmaxf(m, rmaxp[((size_t)NB + b) * NA + i]);
        m = fmaxf(m, rmaxp[((size_t)2 * NB + b) * NA + i]);
        m = fmaxf(m, rmaxp[((size_t)3 * NB + b) * NA + i]);
        vals[i] = m;
    }
    __syncthreads();

    for (int it = 0; it < 10; ++it) {
        float best = -1e30f;
        int bi = 0;
        #pragma unroll
        for (int u = 0; u < 4; ++u) {
            int i = u * 256 + tid;
            if (vals[i] > best) { best = vals[i]; bi = i; }
        }
        #pragma unroll
        for (int off = 32; off; off >>= 1) {
            float ob = __shfl_down(best, off);
            int oi = __shfl_down(bi, off);
            if (ob > best) { best = ob; bi = oi; }
        }
        if (lane == 0) { rv[wv] = best; ri[wv] = bi; }
        __syncthreads();
        if (tid == 0) {
            float bb = rv[0]; int bbi = ri[0];
            #pragma unroll
            for (int k = 1; k < 4; ++k)
                if (rv[k] > bb) { bb = rv[k]; bbi = ri[k]; }
            top[it] = bb; vals[bbi] = -1e30f;
        }
        __syncthreads();
    }

    if (tid < 10) {
        float s = ff1_b[tid];
        #pragma unroll
        for (int i = 0; i < 10; ++i) s += top[i] * ff1_w[i * 10 + tid];
        h[tid] = fmaxf(s, 0.f);
    }
    __syncthreads();
    if (tid == 0) {
        float s = ff2_b[0];
        #pragma unroll
        for (int j = 0; j < 10; ++j) s += h[j] * ff2_w[j];
        out[b] = s;
    }
}

// ---------------- launch ----------------------------------------------------
extern "C" void kernel_launch(void* const* d_in, const int* in_sizes, int n_in,
                              void* d_out, int out_size, void* d_ws, size_t ws_size,
                              hipStream_t stream) {
    const int*   art_w = (const int*)d_in[0];
    const int*   tpl_w = (const int*)d_in[2];
    const float* amask = (const float*)d_in[4];
    const float* tmask = (const float*)d_in[5];
    const float* emb   = (const float*)d_in[6];
    const float* exp_w = (const float*)d_in[7];
    const float* exp_b = (const float*)d_in[8];
    const float* ref_w = (const float*)d_in[9];
    const float* ref_b = (const float*)d_in[10];
    const float* ff1_w = (const float*)d_in[11];
    const float* ff1_b = (const float*)d_in[12];
    const float* ff2_w = (const float*)d_in[13];
    const float* ff2_b = (const float*)d_in[14];
    float* out = (float*)d_out;

    const size_t art_bytes = (size_t)NB * 32 * (NA + 2 * PAD) * 8 * 2;
    const size_t tpl_bytes = (size_t)NB * 32 * (NT + 2 * PAD) * 8 * 2;
    const size_t wpk_bytes = (size_t)10 * 4 * 3 * 8 * 4 * 128 * 8 * 2;

    char* p = (char*)d_ws;
    ushort* art_a = (ushort*)p; p += art_bytes;
    ushort* art_b = (ushort*)p; p += art_bytes;
    ushort* tpl_a = (ushort*)p; p += tpl_bytes;
    ushort* tpl_b = (ushort*)p; p += tpl_bytes;
    ushort* wpack = (ushort*)p; p += wpk_bytes;
    float* a2    = (float*)p; p += (size_t)NB * NA * 4;
    float* t2    = (float*)p; p += (size_t)NB * NT * 4;
    float* rmaxp = (float*)p; p += (size_t)4 * NB * NA * 4;

    // 2048 art + 1024 tpl + 512 pad + 24 sqzero + 960 repack = 4568 blocks
    setup_kernel<<<4568, 256, 0, stream>>>(art_w, tpl_w, emb,
                                           art_a, art_b, tpl_a, tpl_b,
                                           exp_w, ref_w, wpack, a2, t2);

    const int dils[10] = {1, 2, 4, 8, 16, 32, 32, 1, 1, 1};

    ushort* a_cur = art_a; ushort* a_nxt = art_b;
    ushort* t_cur = tpl_a; ushort* t_nxt = tpl_b;
    for (int i = 0; i < 10; ++i) {
        const ushort* wl = wpack + (size_t)i * 4 * 98304;
        const float* bb = (i < 7) ? exp_b + (size_t)i * 512
                                  : ref_b + (size_t)(i - 7) * 512;
        conv_glu_mfma<<<768, 256, 0, stream>>>(
            a_cur, a_nxt, t_cur, t_nxt, wl, bb, dils[i], (i == 9) ? 1 : 0, a2, t2);
        ushort* t1 = a_cur; a_cur = a_nxt; a_nxt = t1;
        ushort* t2p = t_cur; t_cur = t_nxt; t_nxt = t2p;
    }
    ushort* art_fin = a_cur;
    ushort* tpl_fin = t_cur;

    dist_rowmax_mfma<<<1024, 256, 0, stream>>>(
        art_fin, tpl_fin, a2, t2, amask, tmask, rmaxp);

    topk_mlp_kernel<<<NB, 256, 0, stream>>>(rmaxp, ff1_w, ff1_b, ff2_w, ff2_b, out);
}

// Round 9
// 374.753 us; speedup vs baseline: 1.0784x; 1.0784x over previous
//
#include <hip/hip_runtime.h>
#include <math.h>

#define NB 16
#define NA 1024
#define NT 512
#define ND 256
#define PAD 32

typedef short bf8_t __attribute__((ext_vector_type(8)));
typedef float f4_t __attribute__((ext_vector_type(4)));

__device__ __forceinline__ float bf2f(ushort u) {
    union { unsigned int i; float f; } v; v.i = ((unsigned int)u) << 16; return v.f;
}
__device__ __forceinline__ ushort f2bf(float f) {
    union { float f; unsigned int i; } v; v.f = f;
    unsigned int x = v.i;
    unsigned int r = (x + 0x7fffu + ((x >> 16) & 1u)) >> 16;
    return (ushort)r;
}
__device__ __forceinline__ void gl_lds16(const void* g, void* l) {
    __builtin_amdgcn_global_load_lds(
        (const __attribute__((address_space(1))) unsigned int*)g,
        (__attribute__((address_space(3))) unsigned int*)l, 16, 0, 0);
}

// Activation layout (k-major, padded): chunk(b, qq, l_phys) at
//   ((b*32 + qq)*Lp + l_phys)*8 ushorts, qq = ch>>3, Lp = L + 64.

// ---------------- setup: gathers + pad zero + a2/t2 zero + weight repack ----
__global__ void __launch_bounds__(256)
setup_kernel(const int* __restrict__ art_w, const int* __restrict__ tpl_w,
             const float* __restrict__ emb,
             ushort* __restrict__ art_a, ushort* __restrict__ art_b,
             ushort* __restrict__ tpl_a, ushort* __restrict__ tpl_b,
             const float* __restrict__ exp_w, const float* __restrict__ ref_w,
             ushort* __restrict__ wpack,
             float* __restrict__ a2, float* __restrict__ t2) {
    __shared__ float tile[64][65];
    int bid = blockIdx.x;
    int tid = threadIdx.x;

    if (bid < 2048) {                       // article gather
        int idx = bid * 256 + tid;
        int l = idx & (NA - 1);
        int bq = idx >> 10;
        int qq = bq & 31, b = bq >> 5;
        int wd = art_w[b * NA + l];
        const float4* src = (const float4*)(emb + (size_t)wd * ND + qq * 8);
        float4 v0 = src[0], v1 = src[1];
        ushort o[8];
        o[0]=f2bf(v0.x); o[1]=f2bf(v0.y); o[2]=f2bf(v0.z); o[3]=f2bf(v0.w);
        o[4]=f2bf(v1.x); o[5]=f2bf(v1.y); o[6]=f2bf(v1.z); o[7]=f2bf(v1.w);
        *(uint4*)(art_a + ((size_t)bq * (NA + 64) + PAD + l) * 8) = *(uint4*)o;
        return;
    }
    bid -= 2048;
    if (bid < 1024) {                       // template gather
        int j = bid * 256 + tid;
        int l = j & (NT - 1);
        int bq = j >> 9;
        int qq = bq & 31, b = bq >> 5;
        int wd = tpl_w[b * NT + l];
        const float4* src = (const float4*)(emb + (size_t)wd * ND + qq * 8);
        float4 v0 = src[0], v1 = src[1];
        ushort o[8];
        o[0]=f2bf(v0.x); o[1]=f2bf(v0.y); o[2]=f2bf(v0.z); o[3]=f2bf(v0.w);
        o[4]=f2bf(v1.x); o[5]=f2bf(v1.y); o[6]=f2bf(v1.z); o[7]=f2bf(v1.w);
        *(uint4*)(tpl_a + ((size_t)bq * (NT + 64) + PAD + l) * 8) = *(uint4*)o;
        return;
    }
    bid -= 1024;
    if (bid < 512) {                        // pad zeroing
        int j = bid * 256 + tid;
        int y = j >> 15;
        int rem = j & 32767;
        ushort* p = (y == 0) ? art_a : (y == 1) ? art_b : (y == 2) ? tpl_a : tpl_b;
        int L = (y < 2) ? NA : NT;
        int Lp = L + 2 * PAD;
        int plane = rem >> 6;
        int row_in = rem & 63;
        int slab = (row_in < PAD) ? row_in : L + row_in;
        uint4 z = make_uint4(0, 0, 0, 0);
        *(uint4*)(p + ((size_t)plane * Lp + slab) * 8) = z;
        return;
    }
    bid -= 512;
    if (bid < 24) {                         // a2/t2 zeroing (24576 floats)
        int i = (bid * 256 + tid) * 4;
        float4 z = make_float4(0.f, 0.f, 0.f, 0.f);
        if (i < NB * NA) *(float4*)(a2 + i) = z;
        else             *(float4*)(t2 + i - NB * NA) = z;
        return;
    }
    bid -= 24;
    // weight repack: bid in [0,960)
    {
        int li = bid / 96;
        int r = bid % 96;
        int gk = r >> 3;                    // 0..11
        int gc = r & 7;                     // 0..7
        const float* src = (li < 7) ? exp_w + (size_t)li * 3 * ND * 512
                                    : ref_w + (size_t)(li - 7) * 3 * ND * 512;
        int k0g = gk * 64, c0 = gc * 64;
        #pragma unroll
        for (int p = 0; p < 4; ++p) {
            int kr = p * 16 + (tid >> 4);
            int cc = (tid & 15) * 4;
            *(float4*)&tile[kr][cc] =
                *(const float4*)(src + (size_t)(k0g + kr) * 512 + c0 + cc);
        }
        __syncthreads();
        int tap = k0g >> 8, kl0 = k0g & 255, kc0 = kl0 >> 5;
        int ag = c0 >> 8, cb = (c0 & 255) >> 6;
        int kg = tid >> 5, idx = tid & 31;
        int kc = kc0 + (kg >> 2), qq = kg & 3;
        #pragma unroll
        for (int h = 0; h < 2; ++h) {
            int w64 = idx + h * 32;
            int cprime = h * 64 + ag * 32 + idx;
            ushort o[8];
            #pragma unroll
            for (int j = 0; j < 8; ++j) o[j] = f2bf(tile[kg * 8 + j][w64]);
            ushort* d = wpack +
                (((((size_t)(li * 4 + cb) * 3 + tap) * 8 + kc) * 4 + qq) * 128 + cprime) * 8;
            *(uint4*)d = *(uint4*)o;
        }
    }
}

// ---------------- fused conv-GLU-residual, bf16 MFMA (art+tpl fused) --------
// Round-7 structure (best measured): BK=64, 4 blocks/CU, XCD-swizzled grid.
// + fused sum-of-squares on the last layer (atomicAdd into a2/t2).
__global__ void __launch_bounds__(256, 4)
conv_glu_mfma(const ushort* __restrict__ art_x, ushort* __restrict__ art_y,
              const ushort* __restrict__ tpl_x, ushort* __restrict__ tpl_y,
              const ushort* __restrict__ wp, const float* __restrict__ bias,
              int dil, int last, float* __restrict__ a2, float* __restrict__ t2) {
    __shared__ char smem[34816];
    ushort* Als = (ushort*)smem;            // 24 KB: [2][12][512] ushorts
    float* ylds = (float*)smem;             // [128][68] fp32 epilogue

    const int tid = threadIdx.x;
    const int w = tid >> 6, lane = tid & 63;
    const int wm = w >> 1, wn = w & 1;
    const int q = lane >> 4, l15 = lane & 15;

    const int id = blockIdx.x;
    const int cb = (id >> 3) & 3;
    const int pb = ((id >> 5) << 3) | (id & 7);   // 0..191
    const int plane = pb % 12;
    const int b = pb / 12;
    const int b32 = b * 32;

    int Lp, l0;
    const ushort* xb;
    ushort* yb;
    float* sq;
    int sqbase;
    if (plane < 8) {
        Lp = NA + 2 * PAD; l0 = plane * 128;
        xb = art_x; yb = art_y; sq = a2; sqbase = b * NA + l0;
    } else {
        Lp = NT + 2 * PAD; l0 = (plane - 8) * 128;
        xb = tpl_x; yb = tpl_y; sq = t2; sqbase = b * NT + l0;
    }
    const ushort* wl = wp + (size_t)cb * 98304;   // 3*8*4*128*8
    const int boff = (q * 128 + wn * 64 + l15) * 8;

    f4_t acc[4][4];
    #pragma unroll
    for (int i = 0; i < 4; ++i)
        #pragma unroll
        for (int j = 0; j < 4; ++j)
            acc[i][j] = (f4_t){0.f, 0.f, 0.f, 0.f};

    for (int kc2 = 0; kc2 < 4; ++kc2) {
        // --- stage A_ext for 2 sub-chunks: 24 x 1KB gl_lds ---
        #pragma unroll
        for (int s3 = 0; s3 < 6; ++s3) {
            int s = w + s3 * 4;                // 0..23
            int h = s / 12, within = s % 12;
            int qq = kc2 * 8 + h * 4 + within / 3;
            int rphys = l0 + (within % 3) * 64 + lane;
            gl_lds16(xb + ((size_t)(b32 + qq) * Lp + rphys) * 8, Als + s * 512);
        }
        __syncthreads();

        #pragma unroll
        for (int h = 0; h < 2; ++h) {
            const int kc = kc2 * 2 + h;
            const ushort* wkc = wl + kc * 4096 + boff;
            const ushort* Ah = Als + h * 6144;
            #pragma unroll
            for (int t = 0; t < 3; ++t) {
                bf8_t bfr[4];
                #pragma unroll
                for (int nt = 0; nt < 4; ++nt)
                    bfr[nt] = *(const bf8_t*)(wkc + t * 32768 + nt * 128);
                const int sh = (t - 1) * dil;
                bf8_t af[4];
                #pragma unroll
                for (int mt = 0; mt < 4; ++mt)
                    af[mt] = *(const bf8_t*)(Ah + (q * 192 + 32 + sh + wm * 64 + mt * 16 + l15) * 8);
                #pragma unroll
                for (int mt = 0; mt < 4; ++mt)
                    #pragma unroll
                    for (int nt = 0; nt < 4; ++nt)
                        acc[mt][nt] = __builtin_amdgcn_mfma_f32_16x16x32_bf16(
                            af[mt], bfr[nt], acc[mt][nt], 0, 0, 0);
            }
        }
        __syncthreads();
    }

    // GLU epilogue into LDS (fp32), row stride 68 (conflict-free b128 reads)
    #pragma unroll
    for (int nt = 0; nt < 2; ++nt) {
        const int cl = wn * 32 + nt * 16 + l15;
        const int chan = cb * 64 + cl;
        const float ba = bias[chan];
        const float bg2 = bias[chan + 256];
        #pragma unroll
        for (int mt = 0; mt < 4; ++mt) {
            #pragma unroll
            for (int r = 0; r < 4; ++r) {
                const int row = wm * 64 + mt * 16 + q * 4 + r;
                float av = acc[mt][nt][r] + ba;
                float gv = acc[mt][nt + 2][r] + bg2;
                ylds[row * 68 + cl] = av / (1.f + __expf(-gv));
            }
        }
    }
    __syncthreads();

    // residual add + bf16 store, k-major coalesced (+ fused sumsq on last)
    float ss = 0.f;
    #pragma unroll
    for (int p = 0; p < 4; ++p) {
        int u = p * 256 + tid;
        int cl8 = u >> 7;                  // 0..7 plane-chunk within cb
        int row = u & 127;
        size_t go = ((size_t)(b32 + cb * 8 + cl8) * Lp + l0 + PAD + row) * 8;
        ushort xv[8]; *(uint4*)xv = *(const uint4*)(xb + go);
        float4 y0 = *(float4*)&ylds[row * 68 + cl8 * 8];
        float4 y1 = *(float4*)&ylds[row * 68 + cl8 * 8 + 4];
        ushort ov[8];
        ov[0]=f2bf(bf2f(xv[0])+y0.x); ov[1]=f2bf(bf2f(xv[1])+y0.y);
        ov[2]=f2bf(bf2f(xv[2])+y0.z); ov[3]=f2bf(bf2f(xv[3])+y0.w);
        ov[4]=f2bf(bf2f(xv[4])+y1.x); ov[5]=f2bf(bf2f(xv[5])+y1.y);
        ov[6]=f2bf(bf2f(xv[6])+y1.z); ov[7]=f2bf(bf2f(xv[7])+y1.w);
        *(uint4*)(yb + go) = *(uint4*)ov;
        if (last) {
            #pragma unroll
            for (int j = 0; j < 8; ++j) { float f = bf2f(ov[j]); ss += f * f; }
        }
    }
    if (last) {
        float* ssred = (float*)smem;
        __syncthreads();                   // all ylds reads done
        ssred[tid] = ss;
        __syncthreads();
        if (tid < 128)
            atomicAdd(&sq[sqbase + tid], ssred[tid] + ssred[tid + 128]);
    }
}

// ---------------- distance + exp + row max, bf16 MFMA (round-7, M=64) -------
__global__ void __launch_bounds__(256, 4)
dist_rowmax_mfma(const ushort* __restrict__ art, const ushort* __restrict__ tpl,
                 const float* __restrict__ a2, const float* __restrict__ t2,
                 const float* __restrict__ amask, const float* __restrict__ tmask,
                 float* __restrict__ rmaxp) {
    __shared__ ushort Als[64 * 32];    // n = qq*64 + r
    __shared__ ushort Bls[128 * 32];   // n = qq*128 + r
    __shared__ float red[2][64];

    const int tid = threadIdx.x;
    const int w = tid >> 6, lane = tid & 63;
    const int wm = w >> 1, wn = w & 1;
    const int q = lane >> 4, l15 = lane & 15;

    const int id = blockIdx.x;
    const int b = (id & 7) | (((id >> 3) & 1) << 3);
    const int rest = id >> 4;              // 0..63
    const int a0 = (rest & 15) * 64;
    const int tplane = rest >> 4;          // 0..3
    const int t0 = tplane * 128;
    const int b32 = b * 32;
    const int LpA = NA + 2 * PAD, LpT = NT + 2 * PAD;

    float a2v[2][4], amv[2][4];
    #pragma unroll
    for (int mt = 0; mt < 2; ++mt)
        #pragma unroll
        for (int r = 0; r < 4; ++r) {
            int row = a0 + wm * 32 + mt * 16 + q * 4 + r;
            a2v[mt][r] = a2[b * NA + row];
            amv[mt][r] = amask[b * NA + row];
        }

    f4_t acc[2][4];
    #pragma unroll
    for (int i = 0; i < 2; ++i)
        #pragma unroll
        for (int j = 0; j < 4; ++j)
            acc[i][j] = (f4_t){0.f, 0.f, 0.f, 0.f};

    for (int kb = 0; kb < 8; ++kb) {
        #pragma unroll
        for (int s3 = 0; s3 < 3; ++s3) {
            int s = w + s3 * 4;                // 0..11
            if (s < 4) {
                int qq = kb * 4 + s;
                gl_lds16(art + ((size_t)(b32 + qq) * LpA + PAD + a0 + lane) * 8,
                         Als + s * 512);
            } else {
                int s2 = s - 4;
                int qq = kb * 4 + (s2 >> 1);
                int r0 = (s2 & 1) * 64;
                gl_lds16(tpl + ((size_t)(b32 + qq) * LpT + PAD + t0 + r0 + lane) * 8,
                         Bls + s2 * 512);
            }
        }
        __syncthreads();

        bf8_t af[2], bfr[4];
        #pragma unroll
        for (int mt = 0; mt < 2; ++mt)
            af[mt] = *(const bf8_t*)(Als + (q * 64 + wm * 32 + mt * 16 + l15) * 8);
        #pragma unroll
        for (int nt = 0; nt < 4; ++nt)
            bfr[nt] = *(const bf8_t*)(Bls + (q * 128 + wn * 64 + nt * 16 + l15) * 8);
        #pragma unroll
        for (int mt = 0; mt < 2; ++mt)
            #pragma unroll
            for (int nt = 0; nt < 4; ++nt)
                acc[mt][nt] = __builtin_amdgcn_mfma_f32_16x16x32_bf16(
                    af[mt], bfr[nt], acc[mt][nt], 0, 0, 0);
        __syncthreads();
    }

    float rm[2][4];
    #pragma unroll
    for (int mt = 0; mt < 2; ++mt)
        #pragma unroll
        for (int r = 0; r < 4; ++r) rm[mt][r] = 0.f;

    #pragma unroll
    for (int nt = 0; nt < 4; ++nt) {
        int t = t0 + wn * 64 + nt * 16 + l15;
        float t2v = t2[b * NT + t];
        float tmv = tmask[b * NT + t];
        #pragma unroll
        for (int mt = 0; mt < 2; ++mt)
            #pragma unroll
            for (int r = 0; r < 4; ++r) {
                float d = a2v[mt][r] + t2v - 2.f * acc[mt][nt][r];
                d = fmaxf(d, 0.f);
                float s = __expf(-d) * amv[mt][r] * tmv;
                rm[mt][r] = fmaxf(rm[mt][r], s);
            }
    }
    #pragma unroll
    for (int mt = 0; mt < 2; ++mt)
        #pragma unroll
        for (int r = 0; r < 4; ++r) {
            float v = rm[mt][r];
            #pragma unroll
            for (int off = 1; off < 16; off <<= 1)
                v = fmaxf(v, __shfl_xor(v, off));
            rm[mt][r] = v;
        }
    if (l15 == 0) {
        #pragma unroll
        for (int mt = 0; mt < 2; ++mt)
            #pragma unroll
            for (int r = 0; r < 4; ++r)
                red[wn][wm * 32 + mt * 16 + q * 4 + r] = rm[mt][r];
    }
    __syncthreads();
    if (tid < 64)
        rmaxp[((size_t)tplane * NB + b) * NA + a0 + tid] =
            fmaxf(red[0][tid], red[1][tid]);
}

// ---------------- top-10 + MLP ---------------------------------------------
__global__ void __launch_bounds__(256)
topk_mlp_kernel(const float* __restrict__ rmaxp,
                const float* __restrict__ ff1_w, const float* __restrict__ ff1_b,
                const float* __restrict__ ff2_w, const float* __restrict__ ff2_b,
                float* __restrict__ out) {
    __shared__ float vals[NA];
    __shared__ float top[10];
    __shared__ float h[10];
    __shared__ float rv[4];
    __shared__ int ri[4];

    int b = blockIdx.x;
    int tid = threadIdx.x;
    int lane = tid & 63, wv = tid >> 6;
    for (int i = tid; i < NA; i += 256) {
        float m = rmaxp[(size_t)b * NA + i];
        m = fmaxf(m, rmaxp[((size_t)NB + b) * NA + i]);
        m = fmaxf(m, rmaxp[((size_t)2 * NB + b) * NA + i]);
        m = fmaxf(m, rmaxp[((size_t)3 * NB + b) * NA + i]);
        vals[i] = m;
    }
    __syncthreads();

    for (int it = 0; it < 10; ++it) {
        float best = -1e30f;
        int bi = 0;
        #pragma unroll
        for (int u = 0; u < 4; ++u) {
            int i = u * 256 + tid;
            if (vals[i] > best) { best = vals[i]; bi = i; }
        }
        #pragma unroll
        for (int off = 32; off; off >>= 1) {
            float ob = __shfl_down(best, off);
            int oi = __shfl_down(bi, off);
            if (ob > best) { best = ob; bi = oi; }
        }
        if (lane == 0) { rv[wv] = best; ri[wv] = bi; }
        __syncthreads();
        if (tid == 0) {
            float bb = rv[0]; int bbi = ri[0];
            #pragma unroll
            for (int k = 1; k < 4; ++k)
                if (rv[k] > bb) { bb = rv[k]; bbi = ri[k]; }
            top[it] = bb; vals[bbi] = -1e30f;
        }
        __syncthreads();
    }

    if (tid < 10) {
        float s = ff1_b[tid];
        #pragma unroll
        for (int i = 0; i < 10; ++i) s += top[i] * ff1_w[i * 10 + tid];
        h[tid] = fmaxf(s, 0.f);
    }
    __syncthreads();
    if (tid == 0) {
        float s = ff2_b[0];
        #pragma unroll
        for (int j = 0; j < 10; ++j) s += h[j] * ff2_w[j];
        out[b] = s;
    }
}

// ---------------- launch ----------------------------------------------------
extern "C" void kernel_launch(void* const* d_in, const int* in_sizes, int n_in,
                              void* d_out, int out_size, void* d_ws, size_t ws_size,
                              hipStream_t stream) {
    const int*   art_w = (const int*)d_in[0];
    const int*   tpl_w = (const int*)d_in[2];
    const float* amask = (const float*)d_in[4];
    const float* tmask = (const float*)d_in[5];
    const float* emb   = (const float*)d_in[6];
    const float* exp_w = (const float*)d_in[7];
    const float* exp_b = (const float*)d_in[8];
    const float* ref_w = (const float*)d_in[9];
    const float* ref_b = (const float*)d_in[10];
    const float* ff1_w = (const float*)d_in[11];
    const float* ff1_b = (const float*)d_in[12];
    const float* ff2_w = (const float*)d_in[13];
    const float* ff2_b = (const float*)d_in[14];
    float* out = (float*)d_out;

    const size_t art_bytes = (size_t)NB * 32 * (NA + 2 * PAD) * 8 * 2;
    const size_t tpl_bytes = (size_t)NB * 32 * (NT + 2 * PAD) * 8 * 2;
    const size_t wpk_bytes = (size_t)10 * 4 * 3 * 8 * 4 * 128 * 8 * 2;

    char* p = (char*)d_ws;
    ushort* art_a = (ushort*)p; p += art_bytes;
    ushort* art_b = (ushort*)p; p += art_bytes;
    ushort* tpl_a = (ushort*)p; p += tpl_bytes;
    ushort* tpl_b = (ushort*)p; p += tpl_bytes;
    ushort* wpack = (ushort*)p; p += wpk_bytes;
    float* a2    = (float*)p; p += (size_t)NB * NA * 4;
    float* t2    = (float*)p; p += (size_t)NB * NT * 4;
    float* rmaxp = (float*)p; p += (size_t)4 * NB * NA * 4;

    // 2048 art + 1024 tpl + 512 pad + 24 sqzero + 960 repack = 4568 blocks
    setup_kernel<<<4568, 256, 0, stream>>>(art_w, tpl_w, emb,
                                           art_a, art_b, tpl_a, tpl_b,
                                           exp_w, ref_w, wpack, a2, t2);

    const int dils[10] = {1, 2, 4, 8, 16, 32, 32, 1, 1, 1};

    ushort* a_cur = art_a; ushort* a_nxt = art_b;
    ushort* t_cur = tpl_a; ushort* t_nxt = tpl_b;
    for (int i = 0; i < 10; ++i) {
        const ushort* wl = wpack + (size_t)i * 4 * 98304;
        const float* bb = (i < 7) ? exp_b + (size_t)i * 512
                                  : ref_b + (size_t)(i - 7) * 512;
        conv_glu_mfma<<<768, 256, 0, stream>>>(
            a_cur, a_nxt, t_cur, t_nxt, wl, bb, dils[i], (i == 9) ? 1 : 0, a2, t2);
        ushort* t1 = a_cur; a_cur = a_nxt; a_nxt = t1;
        ushort* t2p = t_cur; t_cur = t_nxt; t_nxt = t2p;
    }
    ushort* art_fin = a_cur;
    ushort* tpl_fin = t_cur;

    dist_rowmax_mfma<<<1024, 256, 0, stream>>>(
        art_fin, tpl_fin, a2, t2, amask, tmask, rmaxp);

    topk_mlp_kernel<<<NB, 256, 0, stream>>>(rmaxp, ff1_w, ff1_b, ff2_w, ff2_b, out);
}